// Round 4
// baseline (92.069 us; speedup 1.0000x reference)
//
#include <hip/hip_runtime.h>

// GaussianEdgeGuideV2: edge-guided 3x3 softmax filtering.
// mask: (8,64,128,128) fp32, edge: (8,1,64,64) fp32 -> out (8,64,128,128) fp32.
// Memory-bound: ~75 MB HBM traffic (incl. halo) -> ~12 us floor at 6.3 TB/s.
//
// R4: two-kernel split. Kernel A computes per-pixel softmax weights ONCE
// (was recomputed 8x across channel-group blocks) into 9 planes in d_ws.
// Kernel B streams mask with R2's coalesced dwordx4 + shuffle-halo channel
// loop (depth-1 prefetch, the R2 winner) and has zero transcendental work.

#define THETA 10.0f

constexpr int NB = 8;     // batch
constexpr int C  = 64;    // mask channels
constexpr int H  = 128, W = 128;
constexpr int EH = 64,  EW = 64;

constexpr int ROWS = 8;   // rows per apply-block tile
constexpr int CG   = 8;   // channels per apply block
constexpr int AROWS = 2;  // rows per weight-block tile

// ---------------- Kernel A: per-pixel softmax weights -> 9 planes in ws ----
// grid: (H/AROWS = 64, NB = 8), block = 256 (2 rows x 128 cols, 1 px/thread)
__global__ __launch_bounds__(256) void geg_weights(
    const float* __restrict__ edge,
    float* __restrict__ wp)          // [9][NB][H][W]
{
    __shared__ float e_s[AROWS + 2][W + 4];   // cols 0..W+1 used

    const int t     = threadIdx.x;
    const int ytile = blockIdx.x;
    const int n     = blockIdx.y;
    const int y0    = ytile * AROWS;

    const float* eg = edge + n * (EH * EW);
    const float s = 63.0f / 127.0f;          // (EH-1)/(H-1)
    for (int idx = t; idx < (AROWS + 2) * (W + 2); idx += 256) {
        int rr = idx / (W + 2);
        int cc = idx - rr * (W + 2);
        int gy = y0 - 1 + rr;
        int gx = cc - 1;
        float v = 0.0f;
        if (gy >= 0 && gy < H && gx >= 0 && gx < W) {
            float ys = gy * s;
            float xs = gx * s;
            float yf = floorf(ys), xf = floorf(xs);
            int iy0 = (int)yf, ix0 = (int)xf;
            int iy1 = min(iy0 + 1, EH - 1), ix1 = min(ix0 + 1, EW - 1);
            float wy = ys - yf, wx = xs - xf;
            float tl = eg[iy0 * EW + ix0], tr = eg[iy0 * EW + ix1];
            float bl = eg[iy1 * EW + ix0], br = eg[iy1 * EW + ix1];
            float lv = tl + (bl - tl) * wy;
            float rv = tr + (br - tr) * wy;
            v = lv + (rv - lv) * wx;
        }
        e_s[rr][cc] = v;
    }
    __syncthreads();

    const int xx = t & 127;          // 0..127
    const int rr = t >> 7;           // 0..1
    const int gy = y0 + rr;

    const float c = e_s[rr + 1][xx + 1];
    float a[9], sum = 0.0f;
    #pragma unroll
    for (int di = 0; di < 3; ++di)
        #pragma unroll
        for (int dj = 0; dj < 3; ++dj) {
            float d = c - e_s[rr + di][xx + dj];
            float e = __expf(-THETA * d * d);
            a[di * 3 + dj] = e;
            sum += e;
        }
    const float inv = 1.0f / sum;

    float* o = wp + n * (H * W) + gy * W + xx;
    #pragma unroll
    for (int di = 0; di < 3; ++di)
        #pragma unroll
        for (int dj = 0; dj < 3; ++dj) {
            int ny = gy + di - 1, nx = xx + dj - 1;
            bool ok = (ny >= 0) & (ny < H) & (nx >= 0) & (nx < W);
            int k = di * 3 + dj;
            o[(size_t)k * (NB * H * W)] = ok ? a[k] * inv : 0.0f;
        }
}

// ---------------- Kernel B: streaming apply --------------------------------
// grid: (C/CG = 8, H/ROWS = 16, NB = 8), block = 256
__global__ __launch_bounds__(256) void geg_apply(
    const float* __restrict__ mask,
    const float* __restrict__ wp,    // [9][NB][H][W]
    float* __restrict__ out)
{
    const int t     = threadIdx.x;
    const int cg    = blockIdx.x;
    const int ytile = blockIdx.y;
    const int n     = blockIdx.z;
    const int y0    = ytile * ROWS;

    const int lane = t & 31;
    const int x4   = lane * 4;       // 0,4,...,124
    const int r    = t >> 5;         // 0..7
    const int gy   = y0 + r;

    // 9 coalesced weight loads (4 pixels per thread); OOB already zeroed
    const float* wb = wp + n * (H * W) + gy * W + x4;
    float4 wv[9];
    #pragma unroll
    for (int k = 0; k < 9; ++k)
        wv[k] = *(const float4*)(wb + (size_t)k * (NB * H * W));
    float w[4][9];
    #pragma unroll
    for (int k = 0; k < 9; ++k) {
        w[0][k] = wv[k].x; w[1][k] = wv[k].y; w[2][k] = wv[k].z; w[3][k] = wv[k].w;
    }

    // clamped row offsets (OOB rows have zero weight)
    int rowoff[3];
    rowoff[0] = max(gy - 1, 0) * W + x4;
    rowoff[1] = gy * W + x4;
    rowoff[2] = min(gy + 1, H - 1) * W + x4;

    const int c0 = cg * CG;
    const float* mptr = mask + (size_t)(n * C + c0) * (H * W);
    float*       optr = out  + (size_t)(n * C + c0) * (H * W) + gy * W + x4;

    float4 cur[3];
    #pragma unroll
    for (int i = 0; i < 3; ++i) cur[i] = *(const float4*)(mptr + rowoff[i]);

    #pragma unroll
    for (int ci = 0; ci < CG; ++ci) {
        float4 nxt[3];
        if (ci + 1 < CG) {
            #pragma unroll
            for (int i = 0; i < 3; ++i)
                nxt[i] = *(const float4*)(mptr + H * W + rowoff[i]);
        }

        float av[4] = {0.f, 0.f, 0.f, 0.f};
        #pragma unroll
        for (int i = 0; i < 3; ++i) {
            // 6-wide row window; x-halo via shuffle in the 32-lane row group
            // (edge lanes get junk, but their weight is 0)
            float m6[6];
            m6[0] = __shfl_up(cur[i].w, 1, 32);
            m6[1] = cur[i].x; m6[2] = cur[i].y; m6[3] = cur[i].z; m6[4] = cur[i].w;
            m6[5] = __shfl_down(cur[i].x, 1, 32);
            #pragma unroll
            for (int p = 0; p < 4; ++p) {
                av[p] = fmaf(m6[p + 0], w[p][i * 3 + 0],
                        fmaf(m6[p + 1], w[p][i * 3 + 1],
                        fmaf(m6[p + 2], w[p][i * 3 + 2], av[p])));
            }
        }
        *(float4*)optr = make_float4(av[0], av[1], av[2], av[3]);

        #pragma unroll
        for (int i = 0; i < 3; ++i) cur[i] = nxt[i];
        mptr += H * W;
        optr += H * W;
    }
}

extern "C" void kernel_launch(void* const* d_in, const int* in_sizes, int n_in,
                              void* d_out, int out_size, void* d_ws, size_t ws_size,
                              hipStream_t stream) {
    const float* mask = (const float*)d_in[0];
    const float* edge = (const float*)d_in[1];
    float* out = (float*)d_out;
    float* wp  = (float*)d_ws;       // 9 * 8 * 128 * 128 * 4 B = 4.7 MB

    dim3 gA(H / AROWS, NB);          // 64 x 8 = 512 blocks
    geg_weights<<<gA, 256, 0, stream>>>(edge, wp);

    dim3 gB(C / CG, H / ROWS, NB);   // 8 x 16 x 8 = 1024 blocks
    geg_apply<<<gB, 256, 0, stream>>>(mask, wp, out);
}

// Round 6
// 87.428 us; speedup vs baseline: 1.0531x; 1.0531x over previous
//
#include <hip/hip_runtime.h>

// GaussianEdgeGuideV2: edge-guided 3x3 softmax filtering.
// mask: (8,64,128,128) fp32, edge: (8,1,64,64) fp32 -> out (8,64,128,128) fp32.
// Memory-bound: ~75 MB HBM traffic (incl. halo) -> ~12 us floor at 6.3 TB/s.
//
// R5b (from R2 winner): CG=4 -> 2048 blocks (~24 waves/CU vs 16) and depth-2
// channel prefetch (6 float4 in flight/wave vs 3) to cover load latency.
// Non-temporal stores (via native clang vector type -- HIP float4 rejected by
// the builtin) keep L2 for mask halo reuse.
// R3 lesson: depth-8 prefetch -> VGPR blowup, regression. Keep depth small.

#define THETA 10.0f

typedef float f32x4 __attribute__((ext_vector_type(4)));

constexpr int NB = 8;     // batch
constexpr int C  = 64;    // mask channels
constexpr int H  = 128, W = 128;
constexpr int EH = 64,  EW = 64;

constexpr int ROWS = 8;   // output rows per block tile
constexpr int CG   = 4;   // channels per block (C/CG = 16 groups)

// grid: x = C/CG = 16, y = H/ROWS = 16, z = NB = 8; block = 256
__global__ __launch_bounds__(256) void geg_kernel(
    const float* __restrict__ mask,
    const float* __restrict__ edge,
    float* __restrict__ out)
{
    // upsampled-edge tile with zero border (the unfold's zero padding)
    __shared__ float e_s[ROWS + 2][W + 4];   // fill/read cols 0..W+1

    const int t     = threadIdx.x;
    const int cg    = blockIdx.x;
    const int ytile = blockIdx.y;
    const int n     = blockIdx.z;
    const int y0    = ytile * ROWS;

    // ---- stage bilinear-upsampled edge rows [y0-1, y0+ROWS] x cols [-1, W]
    const float* eg = edge + n * (EH * EW);
    const float s = 63.0f / 127.0f;          // (EH-1)/(H-1)
    for (int idx = t; idx < (ROWS + 2) * (W + 2); idx += 256) {
        int rr = idx / (W + 2);
        int cc = idx - rr * (W + 2);
        int gy = y0 - 1 + rr;
        int gx = cc - 1;
        float v = 0.0f;
        if (gy >= 0 && gy < H && gx >= 0 && gx < W) {
            float ys = gy * s;
            float xs = gx * s;
            float yf = floorf(ys), xf = floorf(xs);
            int iy0 = (int)yf, ix0 = (int)xf;
            int iy1 = min(iy0 + 1, EH - 1), ix1 = min(ix0 + 1, EW - 1);
            float wy = ys - yf, wx = xs - xf;
            float tl = eg[iy0 * EW + ix0], tr = eg[iy0 * EW + ix1];
            float bl = eg[iy1 * EW + ix0], br = eg[iy1 * EW + ix1];
            float lv = tl + (bl - tl) * wy;
            float rv = tr + (br - tr) * wy;
            v = lv + (rv - lv) * wx;
        }
        e_s[rr][cc] = v;
    }
    __syncthreads();

    // ---- each thread: 4 consecutive-x pixels in one row
    const int lane = t & 31;         // position within the 32-lane row group
    const int x4   = lane * 4;       // 0,4,...,124
    const int r    = t >> 5;         // 0..7
    const int gy   = y0 + r;

    // per-pixel softmax weights (OOB neighbors zeroed; denom keeps all 9 terms)
    float w[4][9];
    #pragma unroll
    for (int p = 0; p < 4; ++p) {
        const int gx = x4 + p;
        const float c = e_s[r + 1][gx + 1];
        float a[9], sum = 0.0f;
        #pragma unroll
        for (int di = 0; di < 3; ++di) {
            #pragma unroll
            for (int dj = 0; dj < 3; ++dj) {
                float d = c - e_s[r + di][gx + dj];
                float e = __expf(-THETA * d * d);
                a[di * 3 + dj] = e;
                sum += e;
            }
        }
        const float inv = 1.0f / sum;
        #pragma unroll
        for (int di = 0; di < 3; ++di) {
            #pragma unroll
            for (int dj = 0; dj < 3; ++dj) {
                int ny = gy + di - 1, nx = gx + dj - 1;
                bool ok = (ny >= 0) & (ny < H) & (nx >= 0) & (nx < W);
                w[p][di * 3 + dj] = ok ? a[di * 3 + dj] * inv : 0.0f;
            }
        }
    }

    // clamped row offsets (OOB rows have zero weight; clamp keeps addr in-bounds)
    int rowoff[3];
    rowoff[0] = max(gy - 1, 0) * W + x4;
    rowoff[1] = gy * W + x4;
    rowoff[2] = min(gy + 1, H - 1) * W + x4;

    const int c0 = cg * CG;
    const float* mptr = mask + (size_t)(n * C + c0) * (H * W);
    float*       optr = out  + (size_t)(n * C + c0) * (H * W) + gy * W + x4;

    // depth-2 prefetch: channels ci and ci+1 in flight
    float4 buf[2][3];
    #pragma unroll
    for (int i = 0; i < 3; ++i) {
        buf[0][i] = *(const float4*)(mptr + rowoff[i]);
        buf[1][i] = *(const float4*)(mptr + H * W + rowoff[i]);
    }

    #pragma unroll
    for (int ci = 0; ci < CG; ++ci) {
        float4 cur[3];
        #pragma unroll
        for (int i = 0; i < 3; ++i) cur[i] = buf[ci & 1][i];

        if (ci + 2 < CG) {
            #pragma unroll
            for (int i = 0; i < 3; ++i)
                buf[ci & 1][i] = *(const float4*)(mptr + (ci + 2) * (H * W) + rowoff[i]);
        }

        float av[4] = {0.f, 0.f, 0.f, 0.f};
        #pragma unroll
        for (int i = 0; i < 3; ++i) {
            // 6-wide row window; x-halo via shuffle in the 32-lane row group
            // (edge lanes get junk, but their weight is 0)
            float m6[6];
            m6[0] = __shfl_up(cur[i].w, 1, 32);
            m6[1] = cur[i].x; m6[2] = cur[i].y; m6[3] = cur[i].z; m6[4] = cur[i].w;
            m6[5] = __shfl_down(cur[i].x, 1, 32);
            #pragma unroll
            for (int p = 0; p < 4; ++p) {
                av[p] = fmaf(m6[p + 0], w[p][i * 3 + 0],
                        fmaf(m6[p + 1], w[p][i * 3 + 1],
                        fmaf(m6[p + 2], w[p][i * 3 + 2], av[p])));
            }
        }
        // out is never re-read: non-temporal store keeps L2 for mask halo
        f32x4 o = {av[0], av[1], av[2], av[3]};
        __builtin_nontemporal_store(o, (f32x4*)(optr + ci * (H * W)));
    }
}

extern "C" void kernel_launch(void* const* d_in, const int* in_sizes, int n_in,
                              void* d_out, int out_size, void* d_ws, size_t ws_size,
                              hipStream_t stream) {
    const float* mask = (const float*)d_in[0];
    const float* edge = (const float*)d_in[1];
    float* out = (float*)d_out;

    dim3 grid(C / CG, H / ROWS, NB);   // 16 x 16 x 8 = 2048 blocks
    dim3 block(256);
    geg_kernel<<<grid, block, 0, stream>>>(mask, edge, out);
}

// Round 7
// 84.932 us; speedup vs baseline: 1.0840x; 1.0294x over previous
//
#include <hip/hip_runtime.h>

// GaussianEdgeGuideV2: edge-guided 3x3 softmax filtering.
// mask: (8,64,128,128) fp32, edge: (8,1,64,64) fp32 -> out (8,64,128,128) fp32.
// Memory-bound: ~75 MB HBM traffic (incl. halo) -> ~12 us floor at 6.3 TB/s.
//
// R6 = R2 (CG=8, 1024 blocks, plain stores -- the 85.1us winner) + two
// latency moves sharing one theory:
//   1) issue ch0+ch1 loads BEFORE the edge/weight prologue (prologue ~700cy
//      hides the first load latency; +24 VGPR only -- not R3's +96 blowup)
//   2) depth-2 channel prefetch in the loop (6 dwordx4 in flight/wave).
// Lessons: R3 depth-8 = VGPR blowup; R4 split = launch+ws overhead;
// R5b CG=4+NT = TLP not binding, prologue redundancy costs.

#define THETA 10.0f

constexpr int NB = 8;     // batch
constexpr int C  = 64;    // mask channels
constexpr int H  = 128, W = 128;
constexpr int EH = 64,  EW = 64;

constexpr int ROWS = 8;   // output rows per block tile
constexpr int CG   = 8;   // channels per block (C/CG = 8 groups)

// grid: x = C/CG = 8, y = H/ROWS = 16, z = NB = 8; block = 256
__global__ __launch_bounds__(256) void geg_kernel(
    const float* __restrict__ mask,
    const float* __restrict__ edge,
    float* __restrict__ out)
{
    // upsampled-edge tile with zero border (the unfold's zero padding)
    __shared__ float e_s[ROWS + 2][W + 4];   // fill/read cols 0..W+1

    const int t     = threadIdx.x;
    const int cg    = blockIdx.x;
    const int ytile = blockIdx.y;
    const int n     = blockIdx.z;
    const int y0    = ytile * ROWS;

    // ---- thread geometry: 4 consecutive-x pixels in one row
    const int lane = t & 31;         // position within the 32-lane row group
    const int x4   = lane * 4;       // 0,4,...,124
    const int r    = t >> 5;         // 0..7
    const int gy   = y0 + r;

    // clamped row offsets (OOB rows get zero weight; clamp keeps addr in-bounds)
    int rowoff[3];
    rowoff[0] = max(gy - 1, 0) * W + x4;
    rowoff[1] = gy * W + x4;
    rowoff[2] = min(gy + 1, H - 1) * W + x4;

    const int c0 = cg * CG;
    const float* mptr = mask + (size_t)(n * C + c0) * (H * W);

    // ---- issue ch0+ch1 loads NOW; the prologue below hides their latency
    float4 buf[2][3];
    #pragma unroll
    for (int i = 0; i < 3; ++i) {
        buf[0][i] = *(const float4*)(mptr + rowoff[i]);
        buf[1][i] = *(const float4*)(mptr + H * W + rowoff[i]);
    }

    // ---- stage bilinear-upsampled edge rows [y0-1, y0+ROWS] x cols [-1, W]
    const float* eg = edge + n * (EH * EW);
    const float s = 63.0f / 127.0f;          // (EH-1)/(H-1)
    for (int idx = t; idx < (ROWS + 2) * (W + 2); idx += 256) {
        int rr = idx / (W + 2);
        int cc = idx - rr * (W + 2);
        int egy = y0 - 1 + rr;
        int egx = cc - 1;
        float v = 0.0f;
        if (egy >= 0 && egy < H && egx >= 0 && egx < W) {
            float ys = egy * s;
            float xs = egx * s;
            float yf = floorf(ys), xf = floorf(xs);
            int iy0 = (int)yf, ix0 = (int)xf;
            int iy1 = min(iy0 + 1, EH - 1), ix1 = min(ix0 + 1, EW - 1);
            float wy = ys - yf, wx = xs - xf;
            float tl = eg[iy0 * EW + ix0], tr = eg[iy0 * EW + ix1];
            float bl = eg[iy1 * EW + ix0], br = eg[iy1 * EW + ix1];
            float lv = tl + (bl - tl) * wy;
            float rv = tr + (br - tr) * wy;
            v = lv + (rv - lv) * wx;
        }
        e_s[rr][cc] = v;
    }
    __syncthreads();

    // ---- per-pixel softmax weights (OOB neighbors zeroed; denom keeps all 9)
    float w[4][9];
    #pragma unroll
    for (int p = 0; p < 4; ++p) {
        const int gx = x4 + p;
        const float c = e_s[r + 1][gx + 1];
        float a[9], sum = 0.0f;
        #pragma unroll
        for (int di = 0; di < 3; ++di) {
            #pragma unroll
            for (int dj = 0; dj < 3; ++dj) {
                float d = c - e_s[r + di][gx + dj];
                float e = __expf(-THETA * d * d);
                a[di * 3 + dj] = e;
                sum += e;
            }
        }
        const float inv = 1.0f / sum;
        #pragma unroll
        for (int di = 0; di < 3; ++di) {
            #pragma unroll
            for (int dj = 0; dj < 3; ++dj) {
                int ny = gy + di - 1, nx = gx + dj - 1;
                bool ok = (ny >= 0) & (ny < H) & (nx >= 0) & (nx < W);
                w[p][di * 3 + dj] = ok ? a[di * 3 + dj] * inv : 0.0f;
            }
        }
    }

    // ---- channel loop, depth-2 prefetch
    float* optr = out + (size_t)(n * C + c0) * (H * W) + gy * W + x4;

    #pragma unroll
    for (int ci = 0; ci < CG; ++ci) {
        float4 cur[3];
        #pragma unroll
        for (int i = 0; i < 3; ++i) cur[i] = buf[ci & 1][i];

        if (ci + 2 < CG) {
            #pragma unroll
            for (int i = 0; i < 3; ++i)
                buf[ci & 1][i] = *(const float4*)(mptr + (ci + 2) * (H * W) + rowoff[i]);
        }

        float av[4] = {0.f, 0.f, 0.f, 0.f};
        #pragma unroll
        for (int i = 0; i < 3; ++i) {
            // 6-wide row window; x-halo via shuffle in the 32-lane row group
            // (edge lanes get junk, but their weight is 0)
            float m6[6];
            m6[0] = __shfl_up(cur[i].w, 1, 32);
            m6[1] = cur[i].x; m6[2] = cur[i].y; m6[3] = cur[i].z; m6[4] = cur[i].w;
            m6[5] = __shfl_down(cur[i].x, 1, 32);
            #pragma unroll
            for (int p = 0; p < 4; ++p) {
                av[p] = fmaf(m6[p + 0], w[p][i * 3 + 0],
                        fmaf(m6[p + 1], w[p][i * 3 + 1],
                        fmaf(m6[p + 2], w[p][i * 3 + 2], av[p])));
            }
        }
        *(float4*)(optr + ci * (H * W)) = make_float4(av[0], av[1], av[2], av[3]);
    }
}

extern "C" void kernel_launch(void* const* d_in, const int* in_sizes, int n_in,
                              void* d_out, int out_size, void* d_ws, size_t ws_size,
                              hipStream_t stream) {
    const float* mask = (const float*)d_in[0];
    const float* edge = (const float*)d_in[1];
    float* out = (float*)d_out;

    dim3 grid(C / CG, H / ROWS, NB);   // 8 x 16 x 8 = 1024 blocks
    dim3 block(256);
    geg_kernel<<<grid, block, 0, stream>>>(mask, edge, out);
}